// Round 5
// baseline (296.941 us; speedup 1.0000x reference)
//
#include <hip/hip_runtime.h>

#define BB 4
#define NN 256
#define DD 256
#define HH 256

typedef _Float16 half8 __attribute__((ext_vector_type(8)));
typedef __fp16   fp16x2 __attribute__((ext_vector_type(2)));
typedef float floatx4 __attribute__((ext_vector_type(4)));

// ---------- prep: Wc/Wd -> interleaved f16 (chunk-major)  +  S/T projections ----
// Wf16 layout: [c][h][kkloc], c in [0,8), kkloc in [0,64); kk = 2*d + t.
// Block g: (a) converts W row d=g; (b) computes S/T for rows g*4 .. g*4+3.
#define RPB 4
__global__ __launch_bounds__(256) void prep_kernel(const float* __restrict__ X,
                                                   const float* __restrict__ W1,
                                                   float* __restrict__ S,
                                                   float* __restrict__ T,
                                                   _Float16* __restrict__ Wf16) {
  const int g = blockIdx.x;    // 0..255
  const int h = threadIdx.x;   // 0..255

  // (a) weight conversion for d = g
  {
    const float wc = W1[(size_t)(2 * DD + g) * HH + h];
    const float wd = W1[(size_t)(3 * DD + g) * HH + h];
    const int c  = g >> 5;
    const int dd = g & 31;
    _Float16* p = Wf16 + ((size_t)c * HH * 64 + (size_t)h * 64 + 2 * dd);
    p[0] = (_Float16)wc;   // RTN
    p[1] = (_Float16)wd;
  }

  // (b) S/T for 4 rows
  const int row0 = g * RPB;
  __shared__ float xr[RPB][DD];
#pragma unroll
  for (int r = 0; r < RPB; ++r) xr[r][h] = X[(size_t)(row0 + r) * DD + h];
  __syncthreads();
  const float* __restrict__ Wa = W1;
  const float* __restrict__ Wb = W1 + (size_t)DD * HH;
  float sa[RPB], sb[RPB];
#pragma unroll
  for (int r = 0; r < RPB; ++r) { sa[r] = 0.f; sb[r] = 0.f; }
  for (int d = 0; d < DD; ++d) {
    const float wa = Wa[(size_t)d * HH + h];
    const float wb = Wb[(size_t)d * HH + h];
#pragma unroll
    for (int r = 0; r < RPB; ++r) {
      const float x = xr[r][d];            // LDS broadcast (free)
      sa[r] = fmaf(x, wa, sa[r]);
      sb[r] = fmaf(x, wb, sb[r]);
    }
  }
#pragma unroll
  for (int r = 0; r < RPB; ++r) {
    S[(size_t)(row0 + r) * HH + h] = sa[r];
    T[(size_t)(row0 + r) * HH + h] = sb[r];
  }
}

// ---------- kernel 2: MFMA pair-scores + softmax, one block per (b,i) ----------
// 1024 threads = 16 waves, wave (wr,wc): wr=wid&3 (j), wc=wid>>2 (h).
// Each wave: 4 j-tiles x 4 h-tiles -> acc[4][4] floatx4 = 64 VGPRs.
// __launch_bounds__(1024, 4): 4 waves/EU -> 128-VGPR cap (NOT 64 -> no spill).
__global__ __launch_bounds__(1024, 4) void score_mfma(
    const float* __restrict__ X,  const float* __restrict__ b1,
    const float* __restrict__ W2, const float* __restrict__ b2,
    const float* __restrict__ S,  const float* __restrict__ T,
    const _Float16* __restrict__ Wf16, float* __restrict__ out) {

  const int bi   = blockIdx.x;
  const int b    = bi >> 8;
  const int i    = bi & 255;
  const int t    = threadIdx.x;
  const int lane = t & 63;
  const int wid  = t >> 6;        // 0..15
  const int wr   = wid & 3;       // j-group
  const int wc   = wid >> 2;      // h-group 0..3
  const int q    = lane >> 4;     // 0..3
  const int cc   = lane & 15;     // 0..15

  __shared__ __align__(16) float    xi_s[DD];
  __shared__ __align__(16) _Float16 B_s[HH][72];   // padded rows: 144 B
  __shared__ float pre_s[HH];
  __shared__ float w2_s[HH];
  __shared__ float sc_s[4 * NN];
  __shared__ float red_s[NN];

  if (t < 256) {
    xi_s[t]  = X[(size_t)bi * DD + t];
    pre_s[t] = S[(size_t)bi * HH + t] + b1[t];
    w2_s[t]  = W2[t];
  }

  const float* __restrict__ Xb = X + (size_t)b * NN * DD;
  const float* __restrict__ Tb = T + (size_t)b * NN * HH;

  int xrow_off[4];                 // element offset of row j for each jj
#pragma unroll
  for (int jj = 0; jj < 4; ++jj)
    xrow_off[jj] = ((wr * 4 + jj) * 16 + cc) * DD;

  floatx4 acc[4][4];
#pragma unroll
  for (int jj = 0; jj < 4; ++jj)
#pragma unroll
    for (int hh = 0; hh < 4; ++hh) acc[jj][hh] = (floatx4)0.f;

  // B-chunk staging: 32 KB/chunk, 1024 threads x 32 B.
  const int srow = t >> 2;         // 0..255
  const int sq   = t & 3;          // 0..3
  const uint4* __restrict__ wsrc = (const uint4*)Wf16;   // chunk c at idx c*2048
  const int sidx = srow * 8 + sq * 2;
  uint4 bpre[2];
#pragma unroll
  for (int u = 0; u < 2; ++u) bpre[u] = wsrc[sidx + u];

  for (int ch = 0; ch < 8; ++ch) {
    __syncthreads();                       // previous chunk's reads done
    {
      uint4* bdst = (uint4*)&B_s[srow][sq * 16];
#pragma unroll
      for (int u = 0; u < 2; ++u) bdst[u] = bpre[u];
    }
    if (ch < 7) {
#pragma unroll
      for (int u = 0; u < 2; ++u) bpre[u] = wsrc[(ch + 1) * 2048 + sidx + u];
    }
    __syncthreads();                       // B_s ready

#pragma unroll
    for (int ksl = 0; ksl < 2; ++ksl) {
      const int ks    = ch * 2 + ksl;      // K-step 0..15 (K=32 each)
      const int dbase = ks * 16 + q * 4;   // this lane's 4 d's
      const float4 xiv = *(const float4*)&xi_s[dbase];

      half8 bfrag[4];
#pragma unroll
      for (int hh = 0; hh < 4; ++hh) {
        const int hr = (wc * 4 + hh) * 16 + cc;          // B row n
        bfrag[hh] = *(const half8*)&B_s[hr][ksl * 32 + q * 8];
      }

#pragma unroll
      for (int jj = 0; jj < 4; ++jj) {
        const float4 xj = *(const float4*)(Xb + xrow_off[jj] + dbase);
        union { half8 v; fp16x2 h2[4]; } af;
        af.h2[0] = __builtin_amdgcn_cvt_pkrtz(fabsf(xiv.x - xj.x), xiv.x * xj.x);
        af.h2[1] = __builtin_amdgcn_cvt_pkrtz(fabsf(xiv.y - xj.y), xiv.y * xj.y);
        af.h2[2] = __builtin_amdgcn_cvt_pkrtz(fabsf(xiv.z - xj.z), xiv.z * xj.z);
        af.h2[3] = __builtin_amdgcn_cvt_pkrtz(fabsf(xiv.w - xj.w), xiv.w * xj.w);
#pragma unroll
        for (int hh = 0; hh < 4; ++hh)
          acc[jj][hh] = __builtin_amdgcn_mfma_f32_16x16x32_f16(af.v, bfrag[hh],
                                                               acc[jj][hh], 0, 0, 0);
      }
    }
  }

  // ---- epilogue: add S/T/b1, silu, dot w2, reduce over this wave's 64 h ----
  float psum[4][4];
#pragma unroll
  for (int jj = 0; jj < 4; ++jj)
#pragma unroll
    for (int r = 0; r < 4; ++r) psum[jj][r] = 0.f;

#pragma unroll
  for (int hh = 0; hh < 4; ++hh) {
    const int h = (wc * 4 + hh) * 16 + cc;
    const float w2v = w2_s[h];
    const float pv  = pre_s[h];
#pragma unroll
    for (int jj = 0; jj < 4; ++jj) {
#pragma unroll
      for (int r = 0; r < 4; ++r) {
        const int j = (wr * 4 + jj) * 16 + q * 4 + r;    // C/D row = quad*4+reg
        const float tv = Tb[(size_t)j * HH + h];
        const float hv = acc[jj][hh][r] + pv + tv;
        const float sv = hv * __frcp_rn(1.f + __expf(-hv));  // silu
        psum[jj][r] = fmaf(sv, w2v, psum[jj][r]);
      }
    }
  }

  // reduce over the 16 h-columns (lane bits 0..3), lane cc==0 writes
#pragma unroll
  for (int jj = 0; jj < 4; ++jj) {
#pragma unroll
    for (int r = 0; r < 4; ++r) {
      float v = psum[jj][r];
      v += __shfl_xor(v, 1);
      v += __shfl_xor(v, 2);
      v += __shfl_xor(v, 4);
      v += __shfl_xor(v, 8);
      if (cc == 0) sc_s[wc * NN + (wr * 4 + jj) * 16 + q * 4 + r] = v;
    }
  }
  __syncthreads();

  // ---- softmax over j (first 256 threads active; all hit barriers) ----
  float score = 0.f, e = 0.f;
  if (t < NN) {
    score = sc_s[t] + sc_s[NN + t] + sc_s[2 * NN + t] + sc_s[3 * NN + t] + b2[0];
    if (t == i) score = -1.0e9f;
    red_s[t] = score;
  }
  __syncthreads();
  for (int s = 128; s > 0; s >>= 1) {
    if (t < s) red_s[t] = fmaxf(red_s[t], red_s[t + s]);
    __syncthreads();
  }
  const float m = red_s[0];
  __syncthreads();
  if (t < NN) { e = __expf(score - m); red_s[t] = e; }
  __syncthreads();
  for (int s = 128; s > 0; s >>= 1) {
    if (t < s) red_s[t] += red_s[t + s];
    __syncthreads();
  }
  if (t < NN) out[(size_t)bi * NN + t] = e / red_s[0];
}

extern "C" void kernel_launch(void* const* d_in, const int* in_sizes, int n_in,
                              void* d_out, int out_size, void* d_ws, size_t ws_size,
                              hipStream_t stream) {
  const float* X  = (const float*)d_in[0];
  const float* W1 = (const float*)d_in[1];
  const float* b1 = (const float*)d_in[2];
  const float* W2 = (const float*)d_in[3];
  const float* b2 = (const float*)d_in[4];
  float* out = (float*)d_out;

  float*     Sws  = (float*)d_ws;                                 // 1 MB
  float*     Tws  = Sws + (size_t)BB * NN * HH;                   // 1 MB
  _Float16*  Wf16 = (_Float16*)(Tws + (size_t)BB * NN * HH);      // 256 KB

  prep_kernel<<<256, 256, 0, stream>>>(X, W1, Sws, Tws, Wf16);
  score_mfma<<<BB * NN, 1024, 0, stream>>>(X, b1, W2, b2, Sws, Tws, Wf16, out);
}